// Round 9
// baseline (535.505 us; speedup 1.0000x reference)
//
#include <hip/hip_runtime.h>
#include <hip/hip_cooperative_groups.h>

#define D 16
#define NW_MAX 256
#define CHUNK4 2048   // fallback path chunk

namespace cg = cooperative_groups;

// ===========================================================================
// Fused cooperative kernel, one dispatch:
//   phase 0: zero out (plain float4 stores) + per-block LDS widx-hist
//            -> global bucketTotal
//   phase 1: every block scans the 256 totals identically in LDS; reserves
//            its slots with one gcur atomic per nonempty bucket; scatters its
//            chunk into widx-contiguous perm runs (plain uint2 stores)
//   phase 2: bucketed mm  (verbatim round-4 inner loop, 92.9us proven):
//            W[w] register-cached per block, 16 lanes/edge, shfl-broadcast x,
//            one 64B-line atomicAdd per edge
//   phase 3: fused ReLU (plain float4)
// Cross-phase visibility comes from grid.sync()'s acquire/release fences —
// NO per-element scoped atomics (round-6 lesson: those serialize, 2.3x slower).
// ===========================================================================
__global__ __launch_bounds__(256, 4) void fused_kernel(
    const float* __restrict__ x, const float* __restrict__ W,
    const int* __restrict__ u, const int* __restrict__ v,
    const int* __restrict__ widx, float* __restrict__ out,
    int* __restrict__ bucketTotal, int* __restrict__ gcur,
    uint2* __restrict__ perm, int E, int n4) {
    cg::grid_group grid = cg::this_grid();
    __shared__ int sh[NW_MAX];        // this block's chunk hist
    __shared__ int sc[NW_MAX];        // scan scratch
    __shared__ int sbase[NW_MAX + 1]; // bucket bases (identical in all blocks)
    __shared__ int lb[NW_MAX];        // scatter cursors
    int t = threadIdx.x;
    int b = blockIdx.x;
    int G = gridDim.x;
    float4* out4 = (float4*)out;

    int chunk = (E + G - 1) / G;
    int cbeg = b * chunk; if (cbeg > E) cbeg = E;
    int cend = cbeg + chunk; if (cend > E) cend = E;

    // ---- phase 0 ----------------------------------------------------------
    for (int i = b * 256 + t; i < n4; i += G * 256)
        out4[i] = make_float4(0.f, 0.f, 0.f, 0.f);
    sh[t] = 0;
    __syncthreads();
    for (int k = cbeg + t; k < cend; k += 256)
        atomicAdd(&sh[widx[k]], 1);
    __syncthreads();
    if (sh[t]) atomicAdd(&bucketTotal[t], sh[t]);
    grid.sync();

    // ---- phase 1 ----------------------------------------------------------
    {
        int mine = bucketTotal[t];
        sc[t] = mine;
        __syncthreads();
        for (int d = 1; d < NW_MAX; d <<= 1) {
            int val = sc[t];
            int add = (t >= d) ? sc[t - d] : 0;
            __syncthreads();
            sc[t] = val + add;
            __syncthreads();
        }
        sbase[t] = sc[t] - mine;
        if (t == NW_MAX - 1) sbase[NW_MAX] = sc[t];
        __syncthreads();
        lb[t] = sbase[t] + (sh[t] ? atomicAdd(&gcur[t], sh[t]) : 0);
        __syncthreads();
        for (int k = cbeg + t; k < cend; k += 256) {
            int w = widx[k];
            int pos = atomicAdd(&lb[w], 1);
            perm[pos] = make_uint2((unsigned)u[k], (unsigned)v[k]);
        }
    }
    grid.sync();

    // ---- phase 2: bucketed mm (round-4 proven loop) -----------------------
    {
        int NS = G >> 8;                 // slices per bucket
        int w = b & (NW_MAX - 1);
        int s = b >> 8;
        int bb = sbase[w];
        int cnt = sbase[w + 1] - bb;
        int begin = bb + (int)(((long long)cnt * s) / NS);
        int end   = bb + (int)(((long long)cnt * (s + 1)) / NS);
        int o = t & 15;
        int g = t >> 4;

        const float* Wr = W + ((size_t)w << 8) + (o << 4);
        float4 w0 = *(const float4*)(Wr + 0);
        float4 w1 = *(const float4*)(Wr + 4);
        float4 w2 = *(const float4*)(Wr + 8);
        float4 w3 = *(const float4*)(Wr + 12);

        for (int j = begin + g; j < end; j += 16) {
            uint2 pe = perm[j];
            float xv = x[((size_t)pe.x << 4) + o];
            float a = 0.0f;
            a += w0.x * __shfl(xv,  0, 16);
            a += w0.y * __shfl(xv,  1, 16);
            a += w0.z * __shfl(xv,  2, 16);
            a += w0.w * __shfl(xv,  3, 16);
            a += w1.x * __shfl(xv,  4, 16);
            a += w1.y * __shfl(xv,  5, 16);
            a += w1.z * __shfl(xv,  6, 16);
            a += w1.w * __shfl(xv,  7, 16);
            a += w2.x * __shfl(xv,  8, 16);
            a += w2.y * __shfl(xv,  9, 16);
            a += w2.z * __shfl(xv, 10, 16);
            a += w2.w * __shfl(xv, 11, 16);
            a += w3.x * __shfl(xv, 12, 16);
            a += w3.y * __shfl(xv, 13, 16);
            a += w3.z * __shfl(xv, 14, 16);
            a += w3.w * __shfl(xv, 15, 16);
            atomicAdd(out + ((size_t)pe.y << 4) + o, a);
        }
    }
    grid.sync();

    // ---- phase 3: fused ReLU ----------------------------------------------
    for (int i = b * 256 + t; i < n4; i += G * 256) {
        float4 val = out4[i];
        val.x = fmaxf(val.x, 0.f);
        val.y = fmaxf(val.y, 0.f);
        val.z = fmaxf(val.z, 0.f);
        val.w = fmaxf(val.w, 0.f);
        out4[i] = val;
    }
}

// ===========================================================================
// Fallback 1: proven round-4 multi-kernel pipeline (199 us).
// ===========================================================================
__global__ __launch_bounds__(256) void hist_kernel(
    const int* __restrict__ widx, int* __restrict__ counts, int BP, int E,
    float4* __restrict__ outz, int n4) {
    __shared__ int h[NW_MAX];
    int t = threadIdx.x;
    for (int i = blockIdx.x * 256 + t; i < n4; i += gridDim.x * 256)
        outz[i] = make_float4(0.f, 0.f, 0.f, 0.f);
    h[t] = 0;
    __syncthreads();
    int base = blockIdx.x * CHUNK4;
    int lim = E - base; if (lim > CHUNK4) lim = CHUNK4;
    for (int k = t; k < lim; k += 256)
        atomicAdd(&h[widx[base + k]], 1);
    __syncthreads();
    counts[t * BP + blockIdx.x] = h[t];
}

__global__ __launch_bounds__(256) void rowscan_kernel(
    int* __restrict__ counts, int* __restrict__ rowTotal, int BP, int B) {
    int t = threadIdx.x;
    int w = blockIdx.x * 4 + (t >> 6);
    int lane = t & 63;
    int run = 0;
    for (int b0 = 0; b0 < BP; b0 += 64) {
        int b = b0 + lane;
        int val = (b < B) ? counts[w * BP + b] : 0;
        int incl = val;
        #pragma unroll
        for (int d = 1; d < 64; d <<= 1) {
            int tmp = __shfl_up(incl, d, 64);
            if (lane >= d) incl += tmp;
        }
        if (b < B) counts[w * BP + b] = run + incl - val;
        run += __shfl(incl, 63, 64);
    }
    if (lane == 0) rowTotal[w] = run;
}

__global__ __launch_bounds__(256) void basescan_kernel(
    const int* __restrict__ rowTotal, int* __restrict__ bucketBase) {
    __shared__ int s[NW_MAX];
    int t = threadIdx.x;
    int mine = rowTotal[t];
    s[t] = mine;
    __syncthreads();
    for (int d = 1; d < NW_MAX; d <<= 1) {
        int val = s[t];
        int add = (t >= d) ? s[t - d] : 0;
        __syncthreads();
        s[t] = val + add;
        __syncthreads();
    }
    bucketBase[t] = s[t] - mine;
    if (t == NW_MAX - 1) bucketBase[NW_MAX] = s[t];
}

__global__ __launch_bounds__(256) void scatter_kernel(
    const int* __restrict__ u, const int* __restrict__ v,
    const int* __restrict__ widx, const int* __restrict__ counts,
    const int* __restrict__ bucketBase, uint2* __restrict__ perm,
    int BP, int E) {
    __shared__ int cur[NW_MAX];
    int t = threadIdx.x;
    int b = blockIdx.x;
    cur[t] = bucketBase[t] + counts[t * BP + b];
    __syncthreads();
    int base = b * CHUNK4;
    int lim = E - base; if (lim > CHUNK4) lim = CHUNK4;
    for (int k = t; k < lim; k += 256) {
        int e = base + k;
        int w = widx[e];
        int pos = atomicAdd(&cur[w], 1);
        perm[pos] = make_uint2((unsigned)u[e], (unsigned)v[e]);
    }
}

__global__ __launch_bounds__(256) void bucket_mm_kernel(
    const float* __restrict__ x, const float* __restrict__ W,
    const int* __restrict__ bucketBase, const uint2* __restrict__ perm,
    float* __restrict__ out) {
    int w = blockIdx.x >> 3;
    int s = blockIdx.x & 7;
    int base = bucketBase[w];
    int cnt  = bucketBase[w + 1] - base;
    int begin = base + (cnt * s) / 8;
    int end   = base + (cnt * (s + 1)) / 8;
    int o = threadIdx.x & 15;
    int g = threadIdx.x >> 4;

    const float* Wr = W + ((size_t)w << 8) + (o << 4);
    float4 w0 = *(const float4*)(Wr + 0);
    float4 w1 = *(const float4*)(Wr + 4);
    float4 w2 = *(const float4*)(Wr + 8);
    float4 w3 = *(const float4*)(Wr + 12);

    for (int j = begin + g; j < end; j += 16) {
        uint2 pe = perm[j];
        float xv = x[((size_t)pe.x << 4) + o];
        float a = 0.0f;
        a += w0.x * __shfl(xv,  0, 16);
        a += w0.y * __shfl(xv,  1, 16);
        a += w0.z * __shfl(xv,  2, 16);
        a += w0.w * __shfl(xv,  3, 16);
        a += w1.x * __shfl(xv,  4, 16);
        a += w1.y * __shfl(xv,  5, 16);
        a += w1.z * __shfl(xv,  6, 16);
        a += w1.w * __shfl(xv,  7, 16);
        a += w2.x * __shfl(xv,  8, 16);
        a += w2.y * __shfl(xv,  9, 16);
        a += w2.z * __shfl(xv, 10, 16);
        a += w2.w * __shfl(xv, 11, 16);
        a += w3.x * __shfl(xv, 12, 16);
        a += w3.y * __shfl(xv, 13, 16);
        a += w3.z * __shfl(xv, 14, 16);
        a += w3.w * __shfl(xv, 15, 16);
        atomicAdd(out + ((size_t)pe.y << 4) + o, a);
    }
}

__global__ __launch_bounds__(256) void relu_kernel(float* __restrict__ out, int n4) {
    int i = blockIdx.x * 256 + threadIdx.x;
    if (i >= n4) return;
    float4* p = (float4*)out + i;
    float4 val = *p;
    val.x = fmaxf(val.x, 0.0f);
    val.y = fmaxf(val.y, 0.0f);
    val.z = fmaxf(val.z, 0.0f);
    val.w = fmaxf(val.w, 0.0f);
    *p = val;
}

// Fallback 2: original edge-parallel atomic path.
__global__ __launch_bounds__(256) void edge_scatter_kernel(
    const float* __restrict__ x, const float* __restrict__ W,
    const int* __restrict__ u, const int* __restrict__ v,
    const int* __restrict__ widx, float* __restrict__ out, int E) {
    int tid = blockIdx.x * 256 + threadIdx.x;
    int e = tid >> 4;
    int o = tid & 15;
    if (e >= E) return;
    int w = widx[e], uu = u[e], vv = v[e];
    const float* Wr = W + (size_t)w * (D * D) + (size_t)o * D;
    float4 w0 = *(const float4*)(Wr + 0);
    float4 w1 = *(const float4*)(Wr + 4);
    float4 w2 = *(const float4*)(Wr + 8);
    float4 w3 = *(const float4*)(Wr + 12);
    float xv = x[(size_t)uu * D + o];
    float acc = 0.0f;
    acc += w0.x * __shfl(xv,  0, 16);
    acc += w0.y * __shfl(xv,  1, 16);
    acc += w0.z * __shfl(xv,  2, 16);
    acc += w0.w * __shfl(xv,  3, 16);
    acc += w1.x * __shfl(xv,  4, 16);
    acc += w1.y * __shfl(xv,  5, 16);
    acc += w1.z * __shfl(xv,  6, 16);
    acc += w1.w * __shfl(xv,  7, 16);
    acc += w2.x * __shfl(xv,  8, 16);
    acc += w2.y * __shfl(xv,  9, 16);
    acc += w2.z * __shfl(xv, 10, 16);
    acc += w2.w * __shfl(xv, 11, 16);
    acc += w3.x * __shfl(xv, 12, 16);
    acc += w3.y * __shfl(xv, 13, 16);
    acc += w3.z * __shfl(xv, 14, 16);
    acc += w3.w * __shfl(xv, 15, 16);
    atomicAdd(out + (size_t)vv * D + o, acc);
}

extern "C" void kernel_launch(void* const* d_in, const int* in_sizes, int n_in,
                              void* d_out, int out_size, void* d_ws, size_t ws_size,
                              hipStream_t stream) {
    const float* x    = (const float*)d_in[0];
    const float* W    = (const float*)d_in[1];
    const int*   u    = (const int*)d_in[2];
    const int*   v    = (const int*)d_in[3];
    const int*   widx = (const int*)d_in[4];
    float* out = (float*)d_out;

    int E  = in_sizes[2];
    int NW = in_sizes[1] / (D * D);
    int n4 = out_size / 4;

    // Cooperative grid: multiple of 256 (phase-2 bucket mapping), at most
    // 4 blocks/CU (co-residency guaranteed by __launch_bounds__(256,4)).
    static int s_grid = -1;
    if (s_grid < 0) {
        hipDeviceProp_t prop;
        int dev = 0, maxB = 0;
        hipError_t e0 = hipGetDevice(&dev);
        hipError_t e1 = hipGetDeviceProperties(&prop, dev);
        hipError_t e2 = hipOccupancyMaxActiveBlocksPerMultiprocessor(
            &maxB, fused_kernel, 256, 0);
        if (e0 == hipSuccess && e1 == hipSuccess && e2 == hipSuccess) {
            long long cap = (long long)maxB * prop.multiProcessorCount;
            int ns = (int)(cap / 256);
            if (ns > 4) ns = 4;
            s_grid = (ns >= 1) ? ns * NW_MAX : 0;
        } else {
            s_grid = 0;
        }
    }

    // Fused-path workspace: bucketTotal[256] | gcur[256] | perm[E] uint2
    size_t head = 2048;
    size_t need = head + (size_t)E * 8;

    if (NW <= NW_MAX && s_grid > 0 && ws_size >= need && E > 0) {
        int* bucketTotal = (int*)d_ws;
        int* gcur        = (int*)((char*)d_ws + 1024);
        uint2* perm      = (uint2*)((char*)d_ws + head);

        hipError_t em = hipMemsetAsync(d_ws, 0, head, stream);

        void* args[] = {(void*)&x, (void*)&W, (void*)&u, (void*)&v,
                        (void*)&widx, (void*)&out, (void*)&bucketTotal,
                        (void*)&gcur, (void*)&perm, (void*)&E, (void*)&n4};
        hipError_t err = hipLaunchCooperativeKernel(
            fused_kernel, dim3(s_grid), dim3(256), args, 0, stream);
        if (em == hipSuccess && err == hipSuccess) return;
        s_grid = 0;  // don't retry coop path on later calls
    }

    // Fallback 1: round-4 multi-kernel pipeline (proven 199 us).
    int B  = (E + CHUNK4 - 1) / CHUNK4;
    int BP = (B + 63) & ~63;
    size_t counts_b = (size_t)NW_MAX * BP * 4;
    size_t head2 = counts_b + (size_t)NW_MAX * 4 + 260 * 4;
    size_t need2 = head2 + (size_t)E * 8;

    if (NW <= NW_MAX && ws_size >= need2) {
        int* counts     = (int*)d_ws;
        int* rowTotal   = (int*)((char*)d_ws + counts_b);
        int* bucketBase = (int*)((char*)d_ws + counts_b + (size_t)NW_MAX * 4);
        uint2* perm     = (uint2*)((char*)d_ws + head2);

        hist_kernel<<<B, 256, 0, stream>>>(widx, counts, BP, E, (float4*)out, n4);
        rowscan_kernel<<<64, 256, 0, stream>>>(counts, rowTotal, BP, B);
        basescan_kernel<<<1, 256, 0, stream>>>(rowTotal, bucketBase);
        scatter_kernel<<<B, 256, 0, stream>>>(u, v, widx, counts, bucketBase, perm, BP, E);
        bucket_mm_kernel<<<NW_MAX * 8, 256, 0, stream>>>(x, W, bucketBase, perm, out);
        int rblocks = (n4 + 255) / 256;
        relu_kernel<<<rblocks, 256, 0, stream>>>(out, n4);
    } else {
        // Fallback 2: edge-parallel atomics.
        (void)hipMemsetAsync(d_out, 0, (size_t)out_size * sizeof(float), stream);
        int total_threads = E * 16;
        int blocks = (total_threads + 255) / 256;
        edge_scatter_kernel<<<blocks, 256, 0, stream>>>(x, W, u, v, widx, out, E);
        int rblocks = (n4 + 255) / 256;
        relu_kernel<<<rblocks, 256, 0, stream>>>(out, n4);
    }
}

// Round 10
// 451.081 us; speedup vs baseline: 1.1872x; 1.1872x over previous
//
#include <hip/hip_runtime.h>

#define D 16
#define NW_MAX 256
#define RS_LOG 6
#define RS 64            // nodes per v-range
#define NR_MAX 2048      // supports N <= 131072
#define G1 1024          // build grid
#define NSLICE 8
#define CHUNK4 2048      // fallback chunk

// Header layout in d_ws (ints):
//  [0,256)     wTotal      [256,2304)  rTotal
//  [2304,2560) gcurW       [2560,4608) gcurR
//  [4608,4868) wbase(257)  [4868,6920) rbase(NR+1)
//  [6920]      done
#define HDR_INTS 7168
#define HDR_BYTES (HDR_INTS * 4)

// ===========================================================================
// K1: dual histogram (widx buckets + v-ranges), LDS-aggregated. The LAST
// block to finish scans both totals in LDS and writes wbase/rbase + seeds
// the global cursors (gcurW/gcurR) with the bases — no separate scan kernel.
// ===========================================================================
__global__ __launch_bounds__(256) void build_hist(
    const int* __restrict__ v, const int* __restrict__ widx,
    int* __restrict__ hdr, int E, int NR) {
    int* wTotal = hdr;
    int* rTotal = hdr + 256;
    int* gcurW  = hdr + 2304;
    int* gcurR  = hdr + 2560;
    int* wbase  = hdr + 4608;
    int* rbase  = hdr + 4868;
    int* done   = hdr + 6920;
    __shared__ int shW[NW_MAX];
    __shared__ int shR[NR_MAX];
    __shared__ int sc[256];
    __shared__ int isLast;
    int t = threadIdx.x, b = blockIdx.x;
    shW[t] = 0;
    for (int i = t; i < NR; i += 256) shR[i] = 0;
    __syncthreads();
    int chunk = (E + G1 - 1) / G1;
    int s0 = b * chunk; if (s0 > E) s0 = E;
    int e0 = s0 + chunk; if (e0 > E) e0 = E;
    for (int k = s0 + t; k < e0; k += 256) {
        atomicAdd(&shW[widx[k]], 1);
        atomicAdd(&shR[v[k] >> RS_LOG], 1);
    }
    __syncthreads();
    if (shW[t]) atomicAdd(&wTotal[t], shW[t]);
    for (int i = t; i < NR; i += 256)
        if (shR[i]) atomicAdd(&rTotal[i], shR[i]);
    __threadfence();                          // order hist atomics before done
    __syncthreads();
    if (t == 0) isLast = (atomicAdd(done, 1) == (int)gridDim.x - 1);
    __syncthreads();
    if (!isLast) return;

    // ---- last block only: scan wTotal (256) ----
    int wv = __hip_atomic_load(&wTotal[t], __ATOMIC_RELAXED,
                               __HIP_MEMORY_SCOPE_AGENT);
    sc[t] = wv;
    __syncthreads();
    for (int d = 1; d < 256; d <<= 1) {
        int val = sc[t];
        int add = (t >= d) ? sc[t - d] : 0;
        __syncthreads();
        sc[t] = val + add;
        __syncthreads();
    }
    int wb = sc[t] - wv;
    wbase[t] = wb;
    gcurW[t] = wb;
    if (t == 255) wbase[256] = sc[255];
    __syncthreads();

    // ---- scan rTotal (NR <= 2048): 8 seq elems/thread + 256-scan ----
    int base_i = t * 8;
    int lexc[8];
    int run = 0;
    #pragma unroll
    for (int i = 0; i < 8; ++i) {
        int idx = base_i + i;
        int cv = (idx < NR) ? __hip_atomic_load(&rTotal[idx], __ATOMIC_RELAXED,
                                                __HIP_MEMORY_SCOPE_AGENT) : 0;
        lexc[i] = run;
        run += cv;
    }
    sc[t] = run;
    __syncthreads();
    for (int d = 1; d < 256; d <<= 1) {
        int val = sc[t];
        int add = (t >= d) ? sc[t - d] : 0;
        __syncthreads();
        sc[t] = val + add;
        __syncthreads();
    }
    int tbase = sc[t] - run;
    #pragma unroll
    for (int i = 0; i < 8; ++i) {
        int idx = base_i + i;
        if (idx < NR) {
            int rb = tbase + lexc[i];
            rbase[idx] = rb;
            gcurR[idx] = rb;
        }
    }
    if (t == 255) rbase[NR] = sc[255];
}

// ===========================================================================
// K2: scatter. Per-block LDS hist of both keys, one global reservation atomic
// per nonempty (bucket|range), then LDS-cursor scatter producing:
//   perm[wpos] = (u, vpos)   — widx-sorted work list with v-rank destination
//   vloc8[vpos] = v & 63     — node-in-range tag for the reduce
// ===========================================================================
__global__ __launch_bounds__(256) void build_scatter(
    const int* __restrict__ u, const int* __restrict__ v,
    const int* __restrict__ widx, int* __restrict__ hdr,
    uint2* __restrict__ perm, unsigned char* __restrict__ vloc8,
    int E, int NR) {
    int* gcurW = hdr + 2304;
    int* gcurR = hdr + 2560;
    __shared__ int shW[NW_MAX];
    __shared__ int lbW[NW_MAX];
    __shared__ int shR[NR_MAX];
    __shared__ int lbR[NR_MAX];
    int t = threadIdx.x, b = blockIdx.x;
    shW[t] = 0;
    for (int i = t; i < NR; i += 256) shR[i] = 0;
    __syncthreads();
    int chunk = (E + G1 - 1) / G1;
    int s0 = b * chunk; if (s0 > E) s0 = E;
    int e0 = s0 + chunk; if (e0 > E) e0 = E;
    for (int k = s0 + t; k < e0; k += 256) {
        atomicAdd(&shW[widx[k]], 1);
        atomicAdd(&shR[v[k] >> RS_LOG], 1);
    }
    __syncthreads();
    lbW[t] = shW[t] ? atomicAdd(&gcurW[t], shW[t]) : 0;
    for (int i = t; i < NR; i += 256)
        lbR[i] = shR[i] ? atomicAdd(&gcurR[i], shR[i]) : 0;
    __syncthreads();
    for (int k = s0 + t; k < e0; k += 256) {
        int w = widx[k];
        int vv = v[k];
        int r = vv >> RS_LOG;
        int wpos = atomicAdd(&lbW[w], 1);
        int vpos = atomicAdd(&lbR[r], 1);
        perm[wpos] = make_uint2((unsigned)u[k], (unsigned)vpos);
        vloc8[vpos] = (unsigned char)(vv & (RS - 1));
    }
}

// ===========================================================================
// K3: mm. Proven bucket loop (W register-cached, 16 lanes/edge, shfl x), but
// output is a PLAIN nontemporal 64B store to msg[vpos] — zero atomics.
// ===========================================================================
__global__ __launch_bounds__(256) void mm_msg(
    const float* __restrict__ x, const float* __restrict__ W,
    const int* __restrict__ hdr, const uint2* __restrict__ perm,
    float* __restrict__ msg) {
    const int* wbase = hdr + 4608;
    int w = blockIdx.x >> 3;
    int s = blockIdx.x & 7;
    int base = wbase[w];
    int cnt  = wbase[w + 1] - base;
    int begin = base + (cnt * s) / NSLICE;
    int end   = base + (cnt * (s + 1)) / NSLICE;
    int o = threadIdx.x & 15;
    int g = threadIdx.x >> 4;

    const float* Wr = W + ((size_t)w << 8) + (o << 4);
    float4 w0 = *(const float4*)(Wr + 0);
    float4 w1 = *(const float4*)(Wr + 4);
    float4 w2 = *(const float4*)(Wr + 8);
    float4 w3 = *(const float4*)(Wr + 12);

    for (int j = begin + g; j < end; j += 16) {
        uint2 pe = perm[j];
        float xv = x[((size_t)pe.x << 4) + o];
        float a = 0.0f;
        a += w0.x * __shfl(xv,  0, 16);
        a += w0.y * __shfl(xv,  1, 16);
        a += w0.z * __shfl(xv,  2, 16);
        a += w0.w * __shfl(xv,  3, 16);
        a += w1.x * __shfl(xv,  4, 16);
        a += w1.y * __shfl(xv,  5, 16);
        a += w1.z * __shfl(xv,  6, 16);
        a += w1.w * __shfl(xv,  7, 16);
        a += w2.x * __shfl(xv,  8, 16);
        a += w2.y * __shfl(xv,  9, 16);
        a += w2.z * __shfl(xv, 10, 16);
        a += w2.w * __shfl(xv, 11, 16);
        a += w3.x * __shfl(xv, 12, 16);
        a += w3.y * __shfl(xv, 13, 16);
        a += w3.z * __shfl(xv, 14, 16);
        a += w3.w * __shfl(xv, 15, 16);
        __builtin_nontemporal_store(a, msg + ((size_t)pe.y << 4) + o);
    }
}

// ===========================================================================
// K4: reduce. One block per v-range: stream the range's contiguous message
// run, ds-accumulate into a 64x16 LDS tile, fused ReLU, coalesced store.
// Also covers empty nodes (zeros) — no out memset needed anywhere.
// ===========================================================================
__global__ __launch_bounds__(256) void reduce_relu(
    const float* __restrict__ msg, const unsigned char* __restrict__ vloc8,
    const int* __restrict__ hdr, float* __restrict__ out, int N) {
    const int* rbase = hdr + 4868;
    __shared__ float acc[RS * D];   // 4 KB
    int r = blockIdx.x, t = threadIdx.x;
    for (int i = t; i < RS * D; i += 256) acc[i] = 0.0f;
    __syncthreads();
    int s0 = rbase[r], e0 = rbase[r + 1];
    int o = t & 15, g = t >> 4;
    for (int j = s0 + g; j < e0; j += 16) {
        float val = __builtin_nontemporal_load(msg + ((size_t)j << 4) + o);
        int vl = vloc8[j];
        atomicAdd(&acc[(vl << 4) | o], val);
    }
    __syncthreads();
    int nodeBase = r << RS_LOG;
    int nodes = N - nodeBase; if (nodes > RS) nodes = RS;
    if (nodes <= 0) return;
    int nvec = nodes * (D / 4);
    float4* op = (float4*)(out + ((size_t)nodeBase << 4));
    for (int i = t; i < nvec; i += 256) {
        float4 val = ((float4*)acc)[i];
        val.x = fmaxf(val.x, 0.0f);
        val.y = fmaxf(val.y, 0.0f);
        val.z = fmaxf(val.z, 0.0f);
        val.w = fmaxf(val.w, 0.0f);
        op[i] = val;
    }
}

// ===========================================================================
// Fallback 1: proven round-4 multi-kernel pipeline (199 us).
// ===========================================================================
__global__ __launch_bounds__(256) void hist_kernel(
    const int* __restrict__ widx, int* __restrict__ counts, int BP, int E,
    float4* __restrict__ outz, int n4) {
    __shared__ int h[NW_MAX];
    int t = threadIdx.x;
    for (int i = blockIdx.x * 256 + t; i < n4; i += gridDim.x * 256)
        outz[i] = make_float4(0.f, 0.f, 0.f, 0.f);
    h[t] = 0;
    __syncthreads();
    int base = blockIdx.x * CHUNK4;
    int lim = E - base; if (lim > CHUNK4) lim = CHUNK4;
    for (int k = t; k < lim; k += 256)
        atomicAdd(&h[widx[base + k]], 1);
    __syncthreads();
    counts[t * BP + blockIdx.x] = h[t];
}

__global__ __launch_bounds__(256) void rowscan_kernel(
    int* __restrict__ counts, int* __restrict__ rowTotal, int BP, int B) {
    int t = threadIdx.x;
    int w = blockIdx.x * 4 + (t >> 6);
    int lane = t & 63;
    int run = 0;
    for (int b0 = 0; b0 < BP; b0 += 64) {
        int b = b0 + lane;
        int val = (b < B) ? counts[w * BP + b] : 0;
        int incl = val;
        #pragma unroll
        for (int d = 1; d < 64; d <<= 1) {
            int tmp = __shfl_up(incl, d, 64);
            if (lane >= d) incl += tmp;
        }
        if (b < B) counts[w * BP + b] = run + incl - val;
        run += __shfl(incl, 63, 64);
    }
    if (lane == 0) rowTotal[w] = run;
}

__global__ __launch_bounds__(256) void basescan_kernel(
    const int* __restrict__ rowTotal, int* __restrict__ bucketBase) {
    __shared__ int s[NW_MAX];
    int t = threadIdx.x;
    int mine = rowTotal[t];
    s[t] = mine;
    __syncthreads();
    for (int d = 1; d < NW_MAX; d <<= 1) {
        int val = s[t];
        int add = (t >= d) ? s[t - d] : 0;
        __syncthreads();
        s[t] = val + add;
        __syncthreads();
    }
    bucketBase[t] = s[t] - mine;
    if (t == NW_MAX - 1) bucketBase[NW_MAX] = s[t];
}

__global__ __launch_bounds__(256) void scatter_kernel(
    const int* __restrict__ u, const int* __restrict__ v,
    const int* __restrict__ widx, const int* __restrict__ counts,
    const int* __restrict__ bucketBase, uint2* __restrict__ perm,
    int BP, int E) {
    __shared__ int cur[NW_MAX];
    int t = threadIdx.x;
    int b = blockIdx.x;
    cur[t] = bucketBase[t] + counts[t * BP + b];
    __syncthreads();
    int base = b * CHUNK4;
    int lim = E - base; if (lim > CHUNK4) lim = CHUNK4;
    for (int k = t; k < lim; k += 256) {
        int e = base + k;
        int w = widx[e];
        int pos = atomicAdd(&cur[w], 1);
        perm[pos] = make_uint2((unsigned)u[e], (unsigned)v[e]);
    }
}

__global__ __launch_bounds__(256) void bucket_mm_kernel(
    const float* __restrict__ x, const float* __restrict__ W,
    const int* __restrict__ bucketBase, const uint2* __restrict__ perm,
    float* __restrict__ out) {
    int w = blockIdx.x >> 3;
    int s = blockIdx.x & 7;
    int base = bucketBase[w];
    int cnt  = bucketBase[w + 1] - base;
    int begin = base + (cnt * s) / 8;
    int end   = base + (cnt * (s + 1)) / 8;
    int o = threadIdx.x & 15;
    int g = threadIdx.x >> 4;

    const float* Wr = W + ((size_t)w << 8) + (o << 4);
    float4 w0 = *(const float4*)(Wr + 0);
    float4 w1 = *(const float4*)(Wr + 4);
    float4 w2 = *(const float4*)(Wr + 8);
    float4 w3 = *(const float4*)(Wr + 12);

    for (int j = begin + g; j < end; j += 16) {
        uint2 pe = perm[j];
        float xv = x[((size_t)pe.x << 4) + o];
        float a = 0.0f;
        a += w0.x * __shfl(xv,  0, 16);
        a += w0.y * __shfl(xv,  1, 16);
        a += w0.z * __shfl(xv,  2, 16);
        a += w0.w * __shfl(xv,  3, 16);
        a += w1.x * __shfl(xv,  4, 16);
        a += w1.y * __shfl(xv,  5, 16);
        a += w1.z * __shfl(xv,  6, 16);
        a += w1.w * __shfl(xv,  7, 16);
        a += w2.x * __shfl(xv,  8, 16);
        a += w2.y * __shfl(xv,  9, 16);
        a += w2.z * __shfl(xv, 10, 16);
        a += w2.w * __shfl(xv, 11, 16);
        a += w3.x * __shfl(xv, 12, 16);
        a += w3.y * __shfl(xv, 13, 16);
        a += w3.z * __shfl(xv, 14, 16);
        a += w3.w * __shfl(xv, 15, 16);
        atomicAdd(out + ((size_t)pe.y << 4) + o, a);
    }
}

__global__ __launch_bounds__(256) void relu_kernel(float* __restrict__ out, int n4) {
    int i = blockIdx.x * 256 + threadIdx.x;
    if (i >= n4) return;
    float4* p = (float4*)out + i;
    float4 val = *p;
    val.x = fmaxf(val.x, 0.0f);
    val.y = fmaxf(val.y, 0.0f);
    val.z = fmaxf(val.z, 0.0f);
    val.w = fmaxf(val.w, 0.0f);
    *p = val;
}

// Fallback 2: original edge-parallel atomic path.
__global__ __launch_bounds__(256) void edge_scatter_kernel(
    const float* __restrict__ x, const float* __restrict__ W,
    const int* __restrict__ u, const int* __restrict__ v,
    const int* __restrict__ widx, float* __restrict__ out, int E) {
    int tid = blockIdx.x * 256 + threadIdx.x;
    int e = tid >> 4;
    int o = tid & 15;
    if (e >= E) return;
    int w = widx[e], uu = u[e], vv = v[e];
    const float* Wr = W + (size_t)w * (D * D) + (size_t)o * D;
    float4 w0 = *(const float4*)(Wr + 0);
    float4 w1 = *(const float4*)(Wr + 4);
    float4 w2 = *(const float4*)(Wr + 8);
    float4 w3 = *(const float4*)(Wr + 12);
    float xv = x[(size_t)uu * D + o];
    float acc = 0.0f;
    acc += w0.x * __shfl(xv,  0, 16);
    acc += w0.y * __shfl(xv,  1, 16);
    acc += w0.z * __shfl(xv,  2, 16);
    acc += w0.w * __shfl(xv,  3, 16);
    acc += w1.x * __shfl(xv,  4, 16);
    acc += w1.y * __shfl(xv,  5, 16);
    acc += w1.z * __shfl(xv,  6, 16);
    acc += w1.w * __shfl(xv,  7, 16);
    acc += w2.x * __shfl(xv,  8, 16);
    acc += w2.y * __shfl(xv,  9, 16);
    acc += w2.z * __shfl(xv, 10, 16);
    acc += w2.w * __shfl(xv, 11, 16);
    acc += w3.x * __shfl(xv, 12, 16);
    acc += w3.y * __shfl(xv, 13, 16);
    acc += w3.z * __shfl(xv, 14, 16);
    acc += w3.w * __shfl(xv, 15, 16);
    atomicAdd(out + (size_t)vv * D + o, acc);
}

extern "C" void kernel_launch(void* const* d_in, const int* in_sizes, int n_in,
                              void* d_out, int out_size, void* d_ws, size_t ws_size,
                              hipStream_t stream) {
    const float* x    = (const float*)d_in[0];
    const float* W    = (const float*)d_in[1];
    const int*   u    = (const int*)d_in[2];
    const int*   v    = (const int*)d_in[3];
    const int*   widx = (const int*)d_in[4];
    float* out = (float*)d_out;

    int E  = in_sizes[2];
    int NW = in_sizes[1] / (D * D);
    int N  = out_size / D;
    int n4 = out_size / 4;
    int NR = (N + RS - 1) >> RS_LOG;

    // Dual-permutation path workspace:
    //   header | vloc8[E] | perm[E] uint2 | msg[E*16] float
    size_t off_vloc = HDR_BYTES;
    size_t off_perm = (off_vloc + (size_t)E + 15) & ~(size_t)15;
    size_t off_msg  = (off_perm + (size_t)E * 8 + 63) & ~(size_t)63;
    size_t need     = off_msg + (size_t)E * 64;

    if (NW <= NW_MAX && NR <= NR_MAX && E > 0 && ws_size >= need) {
        int* hdr = (int*)d_ws;
        unsigned char* vloc8 = (unsigned char*)d_ws + off_vloc;
        uint2* perm = (uint2*)((char*)d_ws + off_perm);
        float* msg  = (float*)((char*)d_ws + off_msg);

        (void)hipMemsetAsync(d_ws, 0, HDR_BYTES, stream);
        build_hist<<<G1, 256, 0, stream>>>(v, widx, hdr, E, NR);
        build_scatter<<<G1, 256, 0, stream>>>(u, v, widx, hdr, perm, vloc8, E, NR);
        mm_msg<<<NW_MAX * NSLICE, 256, 0, stream>>>(x, W, hdr, perm, msg);
        reduce_relu<<<NR, 256, 0, stream>>>(msg, vloc8, hdr, out, N);
        return;
    }

    // Fallback 1: round-4 multi-kernel pipeline (proven 199 us).
    int B  = (E + CHUNK4 - 1) / CHUNK4;
    int BP = (B + 63) & ~63;
    size_t counts_b = (size_t)NW_MAX * BP * 4;
    size_t head2 = counts_b + (size_t)NW_MAX * 4 + 260 * 4;
    size_t need2 = head2 + (size_t)E * 8;

    if (NW <= NW_MAX && ws_size >= need2 && E > 0) {
        int* counts     = (int*)d_ws;
        int* rowTotal   = (int*)((char*)d_ws + counts_b);
        int* bucketBase = (int*)((char*)d_ws + counts_b + (size_t)NW_MAX * 4);
        uint2* perm     = (uint2*)((char*)d_ws + head2);

        hist_kernel<<<B, 256, 0, stream>>>(widx, counts, BP, E, (float4*)out, n4);
        rowscan_kernel<<<64, 256, 0, stream>>>(counts, rowTotal, BP, B);
        basescan_kernel<<<1, 256, 0, stream>>>(rowTotal, bucketBase);
        scatter_kernel<<<B, 256, 0, stream>>>(u, v, widx, counts, bucketBase, perm, BP, E);
        bucket_mm_kernel<<<NW_MAX * 8, 256, 0, stream>>>(x, W, bucketBase, perm, out);
        int rblocks = (n4 + 255) / 256;
        relu_kernel<<<rblocks, 256, 0, stream>>>(out, n4);
    } else {
        // Fallback 2: edge-parallel atomics.
        (void)hipMemsetAsync(d_out, 0, (size_t)out_size * sizeof(float), stream);
        if (E > 0) {
            int total_threads = E * 16;
            int blocks = (total_threads + 255) / 256;
            edge_scatter_kernel<<<blocks, 256, 0, stream>>>(x, W, u, v, widx, out, E);
        }
        int rblocks = (n4 + 255) / 256;
        relu_kernel<<<rblocks, 256, 0, stream>>>(out, n4);
    }
}

// Round 11
// 289.266 us; speedup vs baseline: 1.8513x; 1.5594x over previous
//
#include <hip/hip_runtime.h>

#define D 16
#define NW_MAX 256
#define NXCD 8
#define G1 1024
#define NSLICE 8
#define CHUNK4 2048      // fallback chunk

// hdr layout (ints): wTotal[0,256) | gcurW[256,512) | wbase[512,769) | done[769]
#define HDR_BYTES 4096

// ===========================================================================
// K1: zero the per-XCD output copies (grid-stride float4) + widx histogram.
// The LAST block scans the 256 totals and seeds wbase + gcurW — no separate
// scan dispatch. (last-block pattern HW-proven in round 10's build_hist.)
// ===========================================================================
__global__ __launch_bounds__(256) void k1_hist(
    const int* __restrict__ widx, int* __restrict__ hdr,
    float4* __restrict__ copies4, int E, int ncf4) {
    int* wTotal = hdr;
    int* gcurW  = hdr + 256;
    int* wbase  = hdr + 512;
    int* done   = hdr + 769;
    __shared__ int shW[NW_MAX];
    __shared__ int sc[NW_MAX];
    __shared__ int isLast;
    int t = threadIdx.x, b = blockIdx.x, G = gridDim.x;
    shW[t] = 0;
    for (int i = b * 256 + t; i < ncf4; i += G * 256)
        copies4[i] = make_float4(0.f, 0.f, 0.f, 0.f);
    __syncthreads();
    int chunk = (E + G - 1) / G;
    int s0 = b * chunk; if (s0 > E) s0 = E;
    int e0 = s0 + chunk; if (e0 > E) e0 = E;
    for (int k = s0 + t; k < e0; k += 256)
        atomicAdd(&shW[widx[k]], 1);
    __syncthreads();
    if (shW[t]) atomicAdd(&wTotal[t], shW[t]);
    __threadfence();
    __syncthreads();
    if (t == 0) isLast = (atomicAdd(done, 1) == G - 1);
    __syncthreads();
    if (!isLast) return;

    int wv = __hip_atomic_load(&wTotal[t], __ATOMIC_RELAXED,
                               __HIP_MEMORY_SCOPE_AGENT);
    sc[t] = wv;
    __syncthreads();
    for (int d = 1; d < NW_MAX; d <<= 1) {
        int val = sc[t];
        int add = (t >= d) ? sc[t - d] : 0;
        __syncthreads();
        sc[t] = val + add;
        __syncthreads();
    }
    int wb = sc[t] - wv;
    wbase[t] = wb;
    gcurW[t] = wb;
    if (t == NW_MAX - 1) wbase[NW_MAX] = sc[NW_MAX - 1];
}

// ===========================================================================
// K2: scatter into widx-contiguous runs. Per-block LDS hist, one global
// reservation atomic per nonempty bucket, LDS-cursor scatter. (round-8 proven)
// ===========================================================================
__global__ __launch_bounds__(256) void k2_scatter(
    const int* __restrict__ u, const int* __restrict__ v,
    const int* __restrict__ widx, int* __restrict__ hdr,
    uint2* __restrict__ perm, int E) {
    int* gcurW = hdr + 256;
    __shared__ int shW[NW_MAX];
    __shared__ int lb[NW_MAX];
    int t = threadIdx.x, b = blockIdx.x, G = gridDim.x;
    shW[t] = 0;
    __syncthreads();
    int chunk = (E + G - 1) / G;
    int s0 = b * chunk; if (s0 > E) s0 = E;
    int e0 = s0 + chunk; if (e0 > E) e0 = E;
    for (int k = s0 + t; k < e0; k += 256)
        atomicAdd(&shW[widx[k]], 1);
    __syncthreads();
    lb[t] = shW[t] ? atomicAdd(&gcurW[t], shW[t]) : 0;
    __syncthreads();
    for (int k = s0 + t; k < e0; k += 256) {
        int w = widx[k];
        int pos = atomicAdd(&lb[w], 1);
        perm[pos] = make_uint2((unsigned)u[k], (unsigned)v[k]);
    }
}

// ===========================================================================
// K3: bucketed mm (round-4 proven 92.9us loop) with ONE change: the output
// atomic is WORKGROUP-scope into this XCD's private copy. WG-scope drops the
// cross-XCD coherence write-through -> RMW executes cached in the local L2.
// Correct because copy[xcd] is only ever touched by waves on XCD xcd (one
// L2), and kernel-boundary release publishes it to K4.
// ===========================================================================
__global__ __launch_bounds__(256) void k3_mm(
    const float* __restrict__ x, const float* __restrict__ W,
    const int* __restrict__ hdr, const uint2* __restrict__ perm,
    float* __restrict__ copies, int ntot) {
    const int* wbase = hdr + 512;
    int w = blockIdx.x >> 3;
    int s = blockIdx.x & 7;
    int base = wbase[w];
    int cnt  = wbase[w + 1] - base;
    int begin = base + (cnt * s) / NSLICE;
    int end   = base + (cnt * (s + 1)) / NSLICE;
    int o = threadIdx.x & 15;
    int g = threadIdx.x >> 4;

    unsigned xcd;
    asm volatile("s_getreg_b32 %0, hwreg(HW_REG_XCC_ID)" : "=s"(xcd));
    float* myout = copies + (size_t)(xcd & (NXCD - 1)) * ntot;

    const float* Wr = W + ((size_t)w << 8) + (o << 4);
    float4 w0 = *(const float4*)(Wr + 0);
    float4 w1 = *(const float4*)(Wr + 4);
    float4 w2 = *(const float4*)(Wr + 8);
    float4 w3 = *(const float4*)(Wr + 12);

    for (int j = begin + g; j < end; j += 16) {
        uint2 pe = perm[j];
        float xv = x[((size_t)pe.x << 4) + o];
        float a = 0.0f;
        a += w0.x * __shfl(xv,  0, 16);
        a += w0.y * __shfl(xv,  1, 16);
        a += w0.z * __shfl(xv,  2, 16);
        a += w0.w * __shfl(xv,  3, 16);
        a += w1.x * __shfl(xv,  4, 16);
        a += w1.y * __shfl(xv,  5, 16);
        a += w1.z * __shfl(xv,  6, 16);
        a += w1.w * __shfl(xv,  7, 16);
        a += w2.x * __shfl(xv,  8, 16);
        a += w2.y * __shfl(xv,  9, 16);
        a += w2.z * __shfl(xv, 10, 16);
        a += w2.w * __shfl(xv, 11, 16);
        a += w3.x * __shfl(xv, 12, 16);
        a += w3.y * __shfl(xv, 13, 16);
        a += w3.z * __shfl(xv, 14, 16);
        a += w3.w * __shfl(xv, 15, 16);
        __hip_atomic_fetch_add(myout + ((size_t)pe.y << 4) + o, a,
                               __ATOMIC_RELAXED, __HIP_MEMORY_SCOPE_WORKGROUP);
    }
}

// ===========================================================================
// K4: out = relu(sum of the 8 copies). Streaming, 8 independent loads/elem.
// ===========================================================================
__global__ __launch_bounds__(256) void k4_sum(
    const float4* __restrict__ copies4, float4* __restrict__ out4,
    int n4, int n4c) {
    for (int i = blockIdx.x * 256 + threadIdx.x; i < n4; i += gridDim.x * 256) {
        float4 a = copies4[i];
        float4 b1 = copies4[(size_t)1 * n4c + i];
        float4 b2 = copies4[(size_t)2 * n4c + i];
        float4 b3 = copies4[(size_t)3 * n4c + i];
        float4 b4 = copies4[(size_t)4 * n4c + i];
        float4 b5 = copies4[(size_t)5 * n4c + i];
        float4 b6 = copies4[(size_t)6 * n4c + i];
        float4 b7 = copies4[(size_t)7 * n4c + i];
        a.x = a.x + b1.x + b2.x + b3.x + b4.x + b5.x + b6.x + b7.x;
        a.y = a.y + b1.y + b2.y + b3.y + b4.y + b5.y + b6.y + b7.y;
        a.z = a.z + b1.z + b2.z + b3.z + b4.z + b5.z + b6.z + b7.z;
        a.w = a.w + b1.w + b2.w + b3.w + b4.w + b5.w + b6.w + b7.w;
        a.x = fmaxf(a.x, 0.f);
        a.y = fmaxf(a.y, 0.f);
        a.z = fmaxf(a.z, 0.f);
        a.w = fmaxf(a.w, 0.f);
        out4[i] = a;
    }
}

// ===========================================================================
// Fallback 1: proven round-4 multi-kernel pipeline (199 us).
// ===========================================================================
__global__ __launch_bounds__(256) void hist_kernel(
    const int* __restrict__ widx, int* __restrict__ counts, int BP, int E,
    float4* __restrict__ outz, int n4) {
    __shared__ int h[NW_MAX];
    int t = threadIdx.x;
    for (int i = blockIdx.x * 256 + t; i < n4; i += gridDim.x * 256)
        outz[i] = make_float4(0.f, 0.f, 0.f, 0.f);
    h[t] = 0;
    __syncthreads();
    int base = blockIdx.x * CHUNK4;
    int lim = E - base; if (lim > CHUNK4) lim = CHUNK4;
    for (int k = t; k < lim; k += 256)
        atomicAdd(&h[widx[base + k]], 1);
    __syncthreads();
    counts[t * BP + blockIdx.x] = h[t];
}

__global__ __launch_bounds__(256) void rowscan_kernel(
    int* __restrict__ counts, int* __restrict__ rowTotal, int BP, int B) {
    int t = threadIdx.x;
    int w = blockIdx.x * 4 + (t >> 6);
    int lane = t & 63;
    int run = 0;
    for (int b0 = 0; b0 < BP; b0 += 64) {
        int b = b0 + lane;
        int val = (b < B) ? counts[w * BP + b] : 0;
        int incl = val;
        #pragma unroll
        for (int d = 1; d < 64; d <<= 1) {
            int tmp = __shfl_up(incl, d, 64);
            if (lane >= d) incl += tmp;
        }
        if (b < B) counts[w * BP + b] = run + incl - val;
        run += __shfl(incl, 63, 64);
    }
    if (lane == 0) rowTotal[w] = run;
}

__global__ __launch_bounds__(256) void basescan_kernel(
    const int* __restrict__ rowTotal, int* __restrict__ bucketBase) {
    __shared__ int s[NW_MAX];
    int t = threadIdx.x;
    int mine = rowTotal[t];
    s[t] = mine;
    __syncthreads();
    for (int d = 1; d < NW_MAX; d <<= 1) {
        int val = s[t];
        int add = (t >= d) ? s[t - d] : 0;
        __syncthreads();
        s[t] = val + add;
        __syncthreads();
    }
    bucketBase[t] = s[t] - mine;
    if (t == NW_MAX - 1) bucketBase[NW_MAX] = s[t];
}

__global__ __launch_bounds__(256) void scatter_kernel(
    const int* __restrict__ u, const int* __restrict__ v,
    const int* __restrict__ widx, const int* __restrict__ counts,
    const int* __restrict__ bucketBase, uint2* __restrict__ perm,
    int BP, int E) {
    __shared__ int cur[NW_MAX];
    int t = threadIdx.x;
    int b = blockIdx.x;
    cur[t] = bucketBase[t] + counts[t * BP + b];
    __syncthreads();
    int base = b * CHUNK4;
    int lim = E - base; if (lim > CHUNK4) lim = CHUNK4;
    for (int k = t; k < lim; k += 256) {
        int e = base + k;
        int w = widx[e];
        int pos = atomicAdd(&cur[w], 1);
        perm[pos] = make_uint2((unsigned)u[e], (unsigned)v[e]);
    }
}

__global__ __launch_bounds__(256) void bucket_mm_kernel(
    const float* __restrict__ x, const float* __restrict__ W,
    const int* __restrict__ bucketBase, const uint2* __restrict__ perm,
    float* __restrict__ out) {
    int w = blockIdx.x >> 3;
    int s = blockIdx.x & 7;
    int base = bucketBase[w];
    int cnt  = bucketBase[w + 1] - base;
    int begin = base + (cnt * s) / 8;
    int end   = base + (cnt * (s + 1)) / 8;
    int o = threadIdx.x & 15;
    int g = threadIdx.x >> 4;

    const float* Wr = W + ((size_t)w << 8) + (o << 4);
    float4 w0 = *(const float4*)(Wr + 0);
    float4 w1 = *(const float4*)(Wr + 4);
    float4 w2 = *(const float4*)(Wr + 8);
    float4 w3 = *(const float4*)(Wr + 12);

    for (int j = begin + g; j < end; j += 16) {
        uint2 pe = perm[j];
        float xv = x[((size_t)pe.x << 4) + o];
        float a = 0.0f;
        a += w0.x * __shfl(xv,  0, 16);
        a += w0.y * __shfl(xv,  1, 16);
        a += w0.z * __shfl(xv,  2, 16);
        a += w0.w * __shfl(xv,  3, 16);
        a += w1.x * __shfl(xv,  4, 16);
        a += w1.y * __shfl(xv,  5, 16);
        a += w1.z * __shfl(xv,  6, 16);
        a += w1.w * __shfl(xv,  7, 16);
        a += w2.x * __shfl(xv,  8, 16);
        a += w2.y * __shfl(xv,  9, 16);
        a += w2.z * __shfl(xv, 10, 16);
        a += w2.w * __shfl(xv, 11, 16);
        a += w3.x * __shfl(xv, 12, 16);
        a += w3.y * __shfl(xv, 13, 16);
        a += w3.z * __shfl(xv, 14, 16);
        a += w3.w * __shfl(xv, 15, 16);
        atomicAdd(out + ((size_t)pe.y << 4) + o, a);
    }
}

__global__ __launch_bounds__(256) void relu_kernel(float* __restrict__ out, int n4) {
    int i = blockIdx.x * 256 + threadIdx.x;
    if (i >= n4) return;
    float4* p = (float4*)out + i;
    float4 val = *p;
    val.x = fmaxf(val.x, 0.0f);
    val.y = fmaxf(val.y, 0.0f);
    val.z = fmaxf(val.z, 0.0f);
    val.w = fmaxf(val.w, 0.0f);
    *p = val;
}

// Fallback 2: original edge-parallel atomic path.
__global__ __launch_bounds__(256) void edge_scatter_kernel(
    const float* __restrict__ x, const float* __restrict__ W,
    const int* __restrict__ u, const int* __restrict__ v,
    const int* __restrict__ widx, float* __restrict__ out, int E) {
    int tid = blockIdx.x * 256 + threadIdx.x;
    int e = tid >> 4;
    int o = tid & 15;
    if (e >= E) return;
    int w = widx[e], uu = u[e], vv = v[e];
    const float* Wr = W + (size_t)w * (D * D) + (size_t)o * D;
    float4 w0 = *(const float4*)(Wr + 0);
    float4 w1 = *(const float4*)(Wr + 4);
    float4 w2 = *(const float4*)(Wr + 8);
    float4 w3 = *(const float4*)(Wr + 12);
    float xv = x[(size_t)uu * D + o];
    float acc = 0.0f;
    acc += w0.x * __shfl(xv,  0, 16);
    acc += w0.y * __shfl(xv,  1, 16);
    acc += w0.z * __shfl(xv,  2, 16);
    acc += w0.w * __shfl(xv,  3, 16);
    acc += w1.x * __shfl(xv,  4, 16);
    acc += w1.y * __shfl(xv,  5, 16);
    acc += w1.z * __shfl(xv,  6, 16);
    acc += w1.w * __shfl(xv,  7, 16);
    acc += w2.x * __shfl(xv,  8, 16);
    acc += w2.y * __shfl(xv,  9, 16);
    acc += w2.z * __shfl(xv, 10, 16);
    acc += w2.w * __shfl(xv, 11, 16);
    acc += w3.x * __shfl(xv, 12, 16);
    acc += w3.y * __shfl(xv, 13, 16);
    acc += w3.z * __shfl(xv, 14, 16);
    acc += w3.w * __shfl(xv, 15, 16);
    atomicAdd(out + (size_t)vv * D + o, acc);
}

extern "C" void kernel_launch(void* const* d_in, const int* in_sizes, int n_in,
                              void* d_out, int out_size, void* d_ws, size_t ws_size,
                              hipStream_t stream) {
    const float* x    = (const float*)d_in[0];
    const float* W    = (const float*)d_in[1];
    const int*   u    = (const int*)d_in[2];
    const int*   v    = (const int*)d_in[3];
    const int*   widx = (const int*)d_in[4];
    float* out = (float*)d_out;

    int E  = in_sizes[2];
    int NW = in_sizes[1] / (D * D);
    int ntot = out_size;             // floats in out
    int n4 = out_size / 4;

    // Primary path workspace: hdr(4KB) | copies[8][ntot] f32 | perm[E] uint2
    size_t off_copies = HDR_BYTES;
    size_t copies_b   = (size_t)NXCD * ntot * 4;
    size_t off_perm   = (off_copies + copies_b + 15) & ~(size_t)15;
    size_t need       = off_perm + (size_t)E * 8;

    if (NW <= NW_MAX && E > 0 && (ntot % 16) == 0 && ws_size >= need) {
        int* hdr = (int*)d_ws;
        float4* copies4 = (float4*)((char*)d_ws + off_copies);
        float*  copies  = (float*)((char*)d_ws + off_copies);
        uint2*  perm    = (uint2*)((char*)d_ws + off_perm);
        int ncf4 = NXCD * n4;

        (void)hipMemsetAsync(d_ws, 0, HDR_BYTES, stream);
        k1_hist<<<G1, 256, 0, stream>>>(widx, hdr, copies4, E, ncf4);
        k2_scatter<<<G1, 256, 0, stream>>>(u, v, widx, hdr, perm, E);
        k3_mm<<<NW_MAX * NSLICE, 256, 0, stream>>>(x, W, hdr, perm, copies, ntot);
        k4_sum<<<2048, 256, 0, stream>>>(copies4, (float4*)out, n4, n4);
        return;
    }

    // Fallback 1: round-4 multi-kernel pipeline (proven 199 us).
    int B  = (E + CHUNK4 - 1) / CHUNK4;
    int BP = (B + 63) & ~63;
    size_t counts_b = (size_t)NW_MAX * BP * 4;
    size_t head2 = counts_b + (size_t)NW_MAX * 4 + 260 * 4;
    size_t need2 = head2 + (size_t)E * 8;

    if (NW <= NW_MAX && ws_size >= need2 && E > 0) {
        int* counts     = (int*)d_ws;
        int* rowTotal   = (int*)((char*)d_ws + counts_b);
        int* bucketBase = (int*)((char*)d_ws + counts_b + (size_t)NW_MAX * 4);
        uint2* perm     = (uint2*)((char*)d_ws + head2);

        hist_kernel<<<B, 256, 0, stream>>>(widx, counts, BP, E, (float4*)out, n4);
        rowscan_kernel<<<64, 256, 0, stream>>>(counts, rowTotal, BP, B);
        basescan_kernel<<<1, 256, 0, stream>>>(rowTotal, bucketBase);
        scatter_kernel<<<B, 256, 0, stream>>>(u, v, widx, counts, bucketBase, perm, BP, E);
        bucket_mm_kernel<<<NW_MAX * 8, 256, 0, stream>>>(x, W, bucketBase, perm, out);
        int rblocks = (n4 + 255) / 256;
        relu_kernel<<<rblocks, 256, 0, stream>>>(out, n4);
    } else {
        // Fallback 2: edge-parallel atomics.
        (void)hipMemsetAsync(d_out, 0, (size_t)out_size * sizeof(float), stream);
        if (E > 0) {
            int total_threads = E * 16;
            int blocks = (total_threads + 255) / 256;
            edge_scatter_kernel<<<blocks, 256, 0, stream>>>(x, W, u, v, widx, out, E);
        }
        int rblocks = (n4 + 255) / 256;
        relu_kernel<<<rblocks, 256, 0, stream>>>(out, n4);
    }
}

// Round 12
// 268.491 us; speedup vs baseline: 1.9945x; 1.0774x over previous
//
#include <hip/hip_runtime.h>

#define D 16
#define NW_MAX 256
#define G1 1024
#define NSLICE 8

// hdr layout (ints): wTotal[0,256) | gcurW[256,512) | wbase[512,769) | done[776]
#define HDR_BYTES 4096

// ===========================================================================
// K1: fused {zero out} + {widx histogram} + {last-block scan}.
// Grid-stride float4 zeroing of out (k3's atomics need a zero base; kernel
// boundary guarantees completion before k3). LDS hist per block -> one global
// atomic per nonempty bucket. The LAST block to finish scans the 256 totals
// and seeds wbase + gcurW (pattern correctness-proven rounds 10/11).
// ===========================================================================
__global__ __launch_bounds__(256) void k1_hist(
    const int* __restrict__ widx, int* __restrict__ hdr,
    float4* __restrict__ out4, int E, int n4) {
    int* wTotal = hdr;
    int* gcurW  = hdr + 256;
    int* wbase  = hdr + 512;
    int* done   = hdr + 776;
    __shared__ int shW[NW_MAX];
    __shared__ int sc[NW_MAX];
    __shared__ int isLast;
    int t = threadIdx.x, b = blockIdx.x, G = gridDim.x;
    shW[t] = 0;
    for (int i = b * 256 + t; i < n4; i += G * 256)
        out4[i] = make_float4(0.f, 0.f, 0.f, 0.f);
    __syncthreads();
    int chunk = (E + G - 1) / G;
    int s0 = b * chunk; if (s0 > E) s0 = E;
    int e0 = s0 + chunk; if (e0 > E) e0 = E;
    for (int k = s0 + t; k < e0; k += 256)
        atomicAdd(&shW[widx[k]], 1);
    __syncthreads();
    if (shW[t]) atomicAdd(&wTotal[t], shW[t]);
    __threadfence();
    __syncthreads();
    if (t == 0) isLast = (atomicAdd(done, 1) == G - 1);
    __syncthreads();
    if (!isLast) return;

    int wv = __hip_atomic_load(&wTotal[t], __ATOMIC_RELAXED,
                               __HIP_MEMORY_SCOPE_AGENT);
    sc[t] = wv;
    __syncthreads();
    for (int d = 1; d < NW_MAX; d <<= 1) {
        int val = sc[t];
        int add = (t >= d) ? sc[t - d] : 0;
        __syncthreads();
        sc[t] = val + add;
        __syncthreads();
    }
    int wb = sc[t] - wv;
    wbase[t] = wb;
    gcurW[t] = wb;
    if (t == NW_MAX - 1) wbase[NW_MAX] = sc[NW_MAX - 1];
}

// ===========================================================================
// K2: scatter into widx-contiguous runs. Per-block LDS hist, one global
// reservation atomic per nonempty bucket, LDS-cursor scatter. (proven r8/r11)
// ===========================================================================
__global__ __launch_bounds__(256) void k2_scatter(
    const int* __restrict__ u, const int* __restrict__ v,
    const int* __restrict__ widx, int* __restrict__ hdr,
    uint2* __restrict__ perm, int E) {
    int* gcurW = hdr + 256;
    __shared__ int shW[NW_MAX];
    __shared__ int lb[NW_MAX];
    int t = threadIdx.x, b = blockIdx.x, G = gridDim.x;
    shW[t] = 0;
    __syncthreads();
    int chunk = (E + G - 1) / G;
    int s0 = b * chunk; if (s0 > E) s0 = E;
    int e0 = s0 + chunk; if (e0 > E) e0 = E;
    for (int k = s0 + t; k < e0; k += 256)
        atomicAdd(&shW[widx[k]], 1);
    __syncthreads();
    lb[t] = shW[t] ? atomicAdd(&gcurW[t], shW[t]) : 0;
    __syncthreads();
    for (int k = s0 + t; k < e0; k += 256) {
        int w = widx[k];
        int pos = atomicAdd(&lb[w], 1);
        perm[pos] = make_uint2((unsigned)u[k], (unsigned)v[k]);
    }
}

// ===========================================================================
// K3: bucketed mm — round-4's proven 92.9us loop, direct atomicAdd into out.
// W[w] register-cached per block (lane o holds row o); 16 lanes/edge; x row
// broadcast via __shfl(width 16); one 64B-line atomicAdd per edge.
// ===========================================================================
__global__ __launch_bounds__(256) void k3_mm(
    const float* __restrict__ x, const float* __restrict__ W,
    const int* __restrict__ hdr, const uint2* __restrict__ perm,
    float* __restrict__ out) {
    const int* wbase = hdr + 512;
    int w = blockIdx.x >> 3;
    int s = blockIdx.x & 7;
    int base = wbase[w];
    int cnt  = wbase[w + 1] - base;
    int begin = base + (cnt * s) / NSLICE;
    int end   = base + (cnt * (s + 1)) / NSLICE;
    int o = threadIdx.x & 15;
    int g = threadIdx.x >> 4;

    const float* Wr = W + ((size_t)w << 8) + (o << 4);
    float4 w0 = *(const float4*)(Wr + 0);
    float4 w1 = *(const float4*)(Wr + 4);
    float4 w2 = *(const float4*)(Wr + 8);
    float4 w3 = *(const float4*)(Wr + 12);

    for (int j = begin + g; j < end; j += 16) {
        uint2 pe = perm[j];
        float xv = x[((size_t)pe.x << 4) + o];
        float a = 0.0f;
        a += w0.x * __shfl(xv,  0, 16);
        a += w0.y * __shfl(xv,  1, 16);
        a += w0.z * __shfl(xv,  2, 16);
        a += w0.w * __shfl(xv,  3, 16);
        a += w1.x * __shfl(xv,  4, 16);
        a += w1.y * __shfl(xv,  5, 16);
        a += w1.z * __shfl(xv,  6, 16);
        a += w1.w * __shfl(xv,  7, 16);
        a += w2.x * __shfl(xv,  8, 16);
        a += w2.y * __shfl(xv,  9, 16);
        a += w2.z * __shfl(xv, 10, 16);
        a += w2.w * __shfl(xv, 11, 16);
        a += w3.x * __shfl(xv, 12, 16);
        a += w3.y * __shfl(xv, 13, 16);
        a += w3.z * __shfl(xv, 14, 16);
        a += w3.w * __shfl(xv, 15, 16);
        atomicAdd(out + ((size_t)pe.y << 4) + o, a);
    }
}

__global__ __launch_bounds__(256) void relu_kernel(float* __restrict__ out, int n4) {
    int i = blockIdx.x * 256 + threadIdx.x;
    if (i >= n4) return;
    float4* p = (float4*)out + i;
    float4 val = *p;
    val.x = fmaxf(val.x, 0.0f);
    val.y = fmaxf(val.y, 0.0f);
    val.z = fmaxf(val.z, 0.0f);
    val.w = fmaxf(val.w, 0.0f);
    *p = val;
}

// Fallback: original edge-parallel atomic path (200 us, always correct).
__global__ __launch_bounds__(256) void edge_scatter_kernel(
    const float* __restrict__ x, const float* __restrict__ W,
    const int* __restrict__ u, const int* __restrict__ v,
    const int* __restrict__ widx, float* __restrict__ out, int E) {
    int tid = blockIdx.x * 256 + threadIdx.x;
    int e = tid >> 4;
    int o = tid & 15;
    if (e >= E) return;
    int w = widx[e], uu = u[e], vv = v[e];
    const float* Wr = W + (size_t)w * (D * D) + (size_t)o * D;
    float4 w0 = *(const float4*)(Wr + 0);
    float4 w1 = *(const float4*)(Wr + 4);
    float4 w2 = *(const float4*)(Wr + 8);
    float4 w3 = *(const float4*)(Wr + 12);
    float xv = x[(size_t)uu * D + o];
    float acc = 0.0f;
    acc += w0.x * __shfl(xv,  0, 16);
    acc += w0.y * __shfl(xv,  1, 16);
    acc += w0.z * __shfl(xv,  2, 16);
    acc += w0.w * __shfl(xv,  3, 16);
    acc += w1.x * __shfl(xv,  4, 16);
    acc += w1.y * __shfl(xv,  5, 16);
    acc += w1.z * __shfl(xv,  6, 16);
    acc += w1.w * __shfl(xv,  7, 16);
    acc += w2.x * __shfl(xv,  8, 16);
    acc += w2.y * __shfl(xv,  9, 16);
    acc += w2.z * __shfl(xv, 10, 16);
    acc += w2.w * __shfl(xv, 11, 16);
    acc += w3.x * __shfl(xv, 12, 16);
    acc += w3.y * __shfl(xv, 13, 16);
    acc += w3.z * __shfl(xv, 14, 16);
    acc += w3.w * __shfl(xv, 15, 16);
    atomicAdd(out + (size_t)vv * D + o, acc);
}

extern "C" void kernel_launch(void* const* d_in, const int* in_sizes, int n_in,
                              void* d_out, int out_size, void* d_ws, size_t ws_size,
                              hipStream_t stream) {
    const float* x    = (const float*)d_in[0];
    const float* W    = (const float*)d_in[1];
    const int*   u    = (const int*)d_in[2];
    const int*   v    = (const int*)d_in[3];
    const int*   widx = (const int*)d_in[4];
    float* out = (float*)d_out;

    int E  = in_sizes[2];
    int NW = in_sizes[1] / (D * D);
    int n4 = out_size / 4;

    // Workspace: hdr (4KB) | perm[E] uint2
    size_t need = HDR_BYTES + (size_t)E * 8;

    if (NW <= NW_MAX && E > 0 && (out_size % 16) == 0 && ws_size >= need) {
        int* hdr   = (int*)d_ws;
        uint2* perm = (uint2*)((char*)d_ws + HDR_BYTES);

        (void)hipMemsetAsync(d_ws, 0, HDR_BYTES, stream);
        k1_hist<<<G1, 256, 0, stream>>>(widx, hdr, (float4*)out, E, n4);
        k2_scatter<<<G1, 256, 0, stream>>>(u, v, widx, hdr, perm, E);
        k3_mm<<<NW_MAX * NSLICE, 256, 0, stream>>>(x, W, hdr, perm, out);
        int rblocks = (n4 + 255) / 256;
        relu_kernel<<<rblocks, 256, 0, stream>>>(out, n4);
        return;
    }

    // Fallback: edge-parallel atomics.
    (void)hipMemsetAsync(d_out, 0, (size_t)out_size * sizeof(float), stream);
    if (E > 0) {
        int total_threads = E * 16;
        int blocks = (total_threads + 255) / 256;
        edge_scatter_kernel<<<blocks, 256, 0, stream>>>(x, W, u, v, widx, out, E);
    }
    int rblocks = (n4 + 255) / 256;
    relu_kernel<<<rblocks, 256, 0, stream>>>(out, n4);
}

// Round 13
// 217.639 us; speedup vs baseline: 2.4605x; 1.2337x over previous
//
#include <hip/hip_runtime.h>

#define D 16
#define NW_MAX 256
#define CHUNK 2048
#define NSLICE 8

// hdr layout (ints): wTotal[0,256) | gcur[256,512) | wbase[512,769)
// memset zeroes only the first 2048 bytes (wTotal + gcur).
#define HDR_BYTES 4096

// ===========================================================================
// K1: fused {zero out} + {widx histogram}. Per-block LDS hist over one
// contiguous 2048-edge chunk; one global atomicAdd per nonempty bucket.
// NO fence / done-counter — the kernel boundary publishes wTotal (proven by
// every multi-kernel round; round-12's __threadfence was the build killer).
// ===========================================================================
__global__ __launch_bounds__(256) void k1_hist(
    const int* __restrict__ widx, int* __restrict__ hdr,
    float4* __restrict__ out4, int E, int n4) {
    int* wTotal = hdr;
    __shared__ int shW[NW_MAX];
    int t = threadIdx.x, b = blockIdx.x, G = gridDim.x;
    shW[t] = 0;
    for (int i = b * 256 + t; i < n4; i += G * 256)
        out4[i] = make_float4(0.f, 0.f, 0.f, 0.f);
    __syncthreads();
    int s0 = b * CHUNK;
    int e0 = s0 + CHUNK; if (e0 > E) e0 = E;
    for (int k = s0 + t; k < e0; k += 256)
        atomicAdd(&shW[widx[k]], 1);
    __syncthreads();
    if (shW[t]) atomicAdd(&wTotal[t], shW[t]);
}

// ===========================================================================
// K2: scatter into widx-contiguous runs. Re-hist this block's chunk in LDS;
// replicated 256-wide scan of wTotal (identical in every block, ~1us,
// round-8-proven); one reservation atomic per nonempty bucket on gcur;
// LDS-cursor scatter of (u,v) pairs. Block 0 also writes wbase[257] for K3.
// ===========================================================================
__global__ __launch_bounds__(256) void k2_scatter(
    const int* __restrict__ u, const int* __restrict__ v,
    const int* __restrict__ widx, int* __restrict__ hdr,
    uint2* __restrict__ perm, int E) {
    int* wTotal = hdr;
    int* gcur   = hdr + 256;
    int* wbase  = hdr + 512;
    __shared__ int shW[NW_MAX];
    __shared__ int sc[NW_MAX];
    __shared__ int lb[NW_MAX];
    int t = threadIdx.x, b = blockIdx.x;
    shW[t] = 0;
    __syncthreads();
    int s0 = b * CHUNK;
    int e0 = s0 + CHUNK; if (e0 > E) e0 = E;
    for (int k = s0 + t; k < e0; k += 256)
        atomicAdd(&shW[widx[k]], 1);
    __syncthreads();

    // replicated exclusive scan of global bucket totals
    int tot = wTotal[t];
    sc[t] = tot;
    __syncthreads();
    for (int d = 1; d < NW_MAX; d <<= 1) {
        int val = sc[t];
        int add = (t >= d) ? sc[t - d] : 0;
        __syncthreads();
        sc[t] = val + add;
        __syncthreads();
    }
    int sbase = sc[t] - tot;           // exclusive bucket base
    if (b == 0) {
        wbase[t] = sbase;
        if (t == NW_MAX - 1) wbase[NW_MAX] = sc[NW_MAX - 1];
    }
    lb[t] = sbase + (shW[t] ? atomicAdd(&gcur[t], shW[t]) : 0);
    __syncthreads();

    for (int k = s0 + t; k < e0; k += 256) {
        int w = widx[k];
        int pos = atomicAdd(&lb[w], 1);
        perm[pos] = make_uint2((unsigned)u[k], (unsigned)v[k]);
    }
}

// ===========================================================================
// K3: bucketed mm — round-4's proven 92.9us loop, direct atomicAdd into out.
// W[w] register-cached per block (lane o holds row o); 16 lanes/edge; x row
// broadcast via __shfl(width 16); one 64B-line atomicAdd per edge.
// ===========================================================================
__global__ __launch_bounds__(256) void k3_mm(
    const float* __restrict__ x, const float* __restrict__ W,
    const int* __restrict__ hdr, const uint2* __restrict__ perm,
    float* __restrict__ out) {
    const int* wbase = hdr + 512;
    int w = blockIdx.x >> 3;
    int s = blockIdx.x & 7;
    int base = wbase[w];
    int cnt  = wbase[w + 1] - base;
    int begin = base + (cnt * s) / NSLICE;
    int end   = base + (cnt * (s + 1)) / NSLICE;
    int o = threadIdx.x & 15;
    int g = threadIdx.x >> 4;

    const float* Wr = W + ((size_t)w << 8) + (o << 4);
    float4 w0 = *(const float4*)(Wr + 0);
    float4 w1 = *(const float4*)(Wr + 4);
    float4 w2 = *(const float4*)(Wr + 8);
    float4 w3 = *(const float4*)(Wr + 12);

    for (int j = begin + g; j < end; j += 16) {
        uint2 pe = perm[j];
        float xv = x[((size_t)pe.x << 4) + o];
        float a = 0.0f;
        a += w0.x * __shfl(xv,  0, 16);
        a += w0.y * __shfl(xv,  1, 16);
        a += w0.z * __shfl(xv,  2, 16);
        a += w0.w * __shfl(xv,  3, 16);
        a += w1.x * __shfl(xv,  4, 16);
        a += w1.y * __shfl(xv,  5, 16);
        a += w1.z * __shfl(xv,  6, 16);
        a += w1.w * __shfl(xv,  7, 16);
        a += w2.x * __shfl(xv,  8, 16);
        a += w2.y * __shfl(xv,  9, 16);
        a += w2.z * __shfl(xv, 10, 16);
        a += w2.w * __shfl(xv, 11, 16);
        a += w3.x * __shfl(xv, 12, 16);
        a += w3.y * __shfl(xv, 13, 16);
        a += w3.z * __shfl(xv, 14, 16);
        a += w3.w * __shfl(xv, 15, 16);
        atomicAdd(out + ((size_t)pe.y << 4) + o, a);
    }
}

__global__ __launch_bounds__(256) void relu_kernel(float* __restrict__ out, int n4) {
    int i = blockIdx.x * 256 + threadIdx.x;
    if (i >= n4) return;
    float4* p = (float4*)out + i;
    float4 val = *p;
    val.x = fmaxf(val.x, 0.0f);
    val.y = fmaxf(val.y, 0.0f);
    val.z = fmaxf(val.z, 0.0f);
    val.w = fmaxf(val.w, 0.0f);
    *p = val;
}

// Fallback: original edge-parallel atomic path (200 us, always correct).
__global__ __launch_bounds__(256) void edge_scatter_kernel(
    const float* __restrict__ x, const float* __restrict__ W,
    const int* __restrict__ u, const int* __restrict__ v,
    const int* __restrict__ widx, float* __restrict__ out, int E) {
    int tid = blockIdx.x * 256 + threadIdx.x;
    int e = tid >> 4;
    int o = tid & 15;
    if (e >= E) return;
    int w = widx[e], uu = u[e], vv = v[e];
    const float* Wr = W + (size_t)w * (D * D) + (size_t)o * D;
    float4 w0 = *(const float4*)(Wr + 0);
    float4 w1 = *(const float4*)(Wr + 4);
    float4 w2 = *(const float4*)(Wr + 8);
    float4 w3 = *(const float4*)(Wr + 12);
    float xv = x[(size_t)uu * D + o];
    float acc = 0.0f;
    acc += w0.x * __shfl(xv,  0, 16);
    acc += w0.y * __shfl(xv,  1, 16);
    acc += w0.z * __shfl(xv,  2, 16);
    acc += w0.w * __shfl(xv,  3, 16);
    acc += w1.x * __shfl(xv,  4, 16);
    acc += w1.y * __shfl(xv,  5, 16);
    acc += w1.z * __shfl(xv,  6, 16);
    acc += w1.w * __shfl(xv,  7, 16);
    acc += w2.x * __shfl(xv,  8, 16);
    acc += w2.y * __shfl(xv,  9, 16);
    acc += w2.z * __shfl(xv, 10, 16);
    acc += w2.w * __shfl(xv, 11, 16);
    acc += w3.x * __shfl(xv, 12, 16);
    acc += w3.y * __shfl(xv, 13, 16);
    acc += w3.z * __shfl(xv, 14, 16);
    acc += w3.w * __shfl(xv, 15, 16);
    atomicAdd(out + (size_t)vv * D + o, acc);
}

extern "C" void kernel_launch(void* const* d_in, const int* in_sizes, int n_in,
                              void* d_out, int out_size, void* d_ws, size_t ws_size,
                              hipStream_t stream) {
    const float* x    = (const float*)d_in[0];
    const float* W    = (const float*)d_in[1];
    const int*   u    = (const int*)d_in[2];
    const int*   v    = (const int*)d_in[3];
    const int*   widx = (const int*)d_in[4];
    float* out = (float*)d_out;

    int E  = in_sizes[2];
    int NW = in_sizes[1] / (D * D);
    int n4 = out_size / 4;
    int B  = (E + CHUNK - 1) / CHUNK;

    // Workspace: hdr (4KB) | perm[E] uint2
    size_t need = HDR_BYTES + (size_t)E * 8;

    if (NW <= NW_MAX && E > 0 && (out_size % 16) == 0 && ws_size >= need) {
        int* hdr    = (int*)d_ws;
        uint2* perm = (uint2*)((char*)d_ws + HDR_BYTES);

        (void)hipMemsetAsync(d_ws, 0, 2048, stream);   // wTotal + gcur only
        k1_hist<<<B, 256, 0, stream>>>(widx, hdr, (float4*)out, E, n4);
        k2_scatter<<<B, 256, 0, stream>>>(u, v, widx, hdr, perm, E);
        k3_mm<<<NW_MAX * NSLICE, 256, 0, stream>>>(x, W, hdr, perm, out);
        int rblocks = (n4 + 255) / 256;
        relu_kernel<<<rblocks, 256, 0, stream>>>(out, n4);
        return;
    }

    // Fallback: edge-parallel atomics.
    (void)hipMemsetAsync(d_out, 0, (size_t)out_size * sizeof(float), stream);
    if (E > 0) {
        int total_threads = E * 16;
        int blocks = (total_threads + 255) / 256;
        edge_scatter_kernel<<<blocks, 256, 0, stream>>>(x, W, u, v, widx, out, E);
    }
    int rblocks = (n4 + 255) / 256;
    relu_kernel<<<rblocks, 256, 0, stream>>>(out, n4);
}